// Round 1
// baseline (179.454 us; speedup 1.0000x reference)
//
#include <hip/hip_runtime.h>

// Hawkes log-likelihood, D=1024 dims, M=32768 events, BETA=1.
//
// Closed form: lam_i = mu[d_i] + sum_{j<i} alpha[d_i,d_j] * exp(t_j - t_i).
// Chunk events into NC chunks of C=64. Per event:
//   cross-chunk: exp(t_c0 - t_i) * dot(alpha[d_i,:], S_c)   (S_c = chunk-boundary state)
//   in-chunk:    one lane-parallel predicated gather step (C=64 == wave size)
// S_c computed by a dimension-parallel scan over chunks (factors <= 1, no overflow).
// Compensator: sum_i colsum(alpha)[d_i] * (1 - exp(t_i - T)), fused into main kernel.
//
// ws layout (floats): alpha[D*D] | L/S[NC*D] | mu[D] | colsum[D] | acc[4]
// total ~6.3 MB. acc: [0]=ll_sum [1]=comp_sum [2]=mu_sum

#define D 1024
#define M 32768
#define C 64
#define NC (M / C) /* 512 */
#define TMAXV 1000.0f
#define EPSMU 1e-6f
#define EPSLOG 1e-8f

__device__ __forceinline__ float softplus(float x) {
    return (x > 0.0f) ? (x + log1pf(__expf(-x))) : log1pf(__expf(x));
}

__global__ void k_init(float* __restrict__ colsum, float* __restrict__ acc) {
    int t = threadIdx.x;
#pragma unroll
    for (int q = 0; q < 4; ++q) colsum[t + 256 * q] = 0.0f;
    if (t < 4) acc[t] = 0.0f;
}

// blocks 0..255: softplus(alpha) tile (4 rows x 1024 cols) + column-sum partials
// block 256: mu = softplus(log_mu) + eps, and mu_sum
__global__ void k_prep(const float* __restrict__ log_alpha, const float* __restrict__ log_mu,
                       float* __restrict__ alpha, float* __restrict__ mu,
                       float* __restrict__ colsum, float* __restrict__ acc) {
    int t = threadIdx.x;
    int b = blockIdx.x;
    if (b < 256) {
        int r0 = b * 4;
        float cs[4] = {0.f, 0.f, 0.f, 0.f};
        for (int r = 0; r < 4; ++r) {
            size_t base = (size_t)(r0 + r) * D;
#pragma unroll
            for (int q = 0; q < 4; ++q) {
                int col = t + 256 * q;
                float a = softplus(log_alpha[base + col]);
                alpha[base + col] = a;
                cs[q] += a;
            }
        }
#pragma unroll
        for (int q = 0; q < 4; ++q) atomicAdd(&colsum[t + 256 * q], cs[q]);
    } else {
        float ms = 0.0f;
#pragma unroll
        for (int q = 0; q < 4; ++q) {
            int k = t + 256 * q;
            float m = softplus(log_mu[k]) + EPSMU;
            mu[k] = m;
            ms += m;
        }
        atomicAdd(&acc[2], ms);
    }
}

// per-chunk local excitation histogram, referenced at next chunk's start time
__global__ void k_buildL(const float* __restrict__ t_ev, const int* __restrict__ marks,
                         float* __restrict__ L) {
    __shared__ float Lh[D];
    int t = threadIdx.x, c = blockIdx.x;
#pragma unroll
    for (int q = 0; q < 4; ++q) Lh[t + 256 * q] = 0.0f;
    __syncthreads();
    if (t < C) {
        int g = c * C + t;
        float tn = (c + 1 < NC) ? t_ev[(c + 1) * C] : t_ev[M - 1];
        atomicAdd(&Lh[marks[g]], __expf(t_ev[g] - tn));
    }
    __syncthreads();
#pragma unroll
    for (int q = 0; q < 4; ++q) {
        int k = t + 256 * q;
        L[(size_t)c * D + k] = Lh[k];
    }
}

// dimension-parallel scan over chunks, in place: L[c] becomes S_c (state at chunk start).
// Unrolled x8 so the 512 serial iterations pipeline their independent loads.
__global__ void k_scan(const float* __restrict__ t_ev, float* __restrict__ L) {
    __shared__ float dec[NC];
    int t = threadIdx.x;
    for (int c = t; c < NC; c += 256)
        dec[c] = (c + 1 < NC) ? __expf(t_ev[c * C] - t_ev[(c + 1) * C]) : 1.0f;
    __syncthreads();
    int k = blockIdx.x * 256 + t;  // each thread owns one dimension
    float S = 0.0f;
    for (int c8 = 0; c8 < NC; c8 += 8) {
        float tmp[8];
#pragma unroll
        for (int u = 0; u < 8; ++u) tmp[u] = L[(size_t)(c8 + u) * D + k];
#pragma unroll
        for (int u = 0; u < 8; ++u) {
            L[(size_t)(c8 + u) * D + k] = S;
            S = S * dec[c8 + u] + tmp[u];
        }
    }
}

// main: one block per chunk, one wave per event (round-robin), fused compensator
__launch_bounds__(256)
__global__ void k_main(const float* __restrict__ t_ev, const int* __restrict__ marks,
                       const float* __restrict__ alpha, const float* __restrict__ mu,
                       const float* __restrict__ colsum, const float* __restrict__ S_arr,
                       float* __restrict__ acc) {
    __shared__ float S_lds[D];
    __shared__ float t_lds[C];
    __shared__ int d_lds[C];
    int t = threadIdx.x, c = blockIdx.x;
#pragma unroll
    for (int q = 0; q < 4; ++q) S_lds[t + 256 * q] = S_arr[(size_t)c * D + t + 256 * q];
    if (t < C) {
        t_lds[t] = t_ev[c * C + t];
        d_lds[t] = marks[c * C + t];
    }
    __syncthreads();
    int wave = t >> 6, lane = t & 63;
    float t0 = t_lds[0];
    float ll_acc = 0.0f, comp_acc = 0.0f;
    for (int i = wave; i < C; i += 4) {
        int row = d_lds[i];
        float ti = t_lds[i];
        const float4* arow = (const float4*)(alpha + (size_t)row * D);
        const float4* srow = (const float4*)S_lds;
        float acc_dot = 0.0f;
#pragma unroll
        for (int u = 0; u < 4; ++u) {
            float4 a4 = arow[lane + 64 * u];
            float4 s4 = srow[lane + 64 * u];
            acc_dot += a4.x * s4.x + a4.y * s4.y + a4.z * s4.z + a4.w * s4.w;
        }
        float part = acc_dot * __expf(t0 - ti);
        if (lane < i) {
            part += alpha[(size_t)row * D + d_lds[lane]] * __expf(t_lds[lane] - ti);
        }
#pragma unroll
        for (int off = 32; off > 0; off >>= 1) part += __shfl_xor(part, off);
        if (lane == 0) {
            float lam = mu[row] + part;
            ll_acc += __logf(lam + EPSLOG);
            comp_acc += colsum[row] * (1.0f - __expf(ti - TMAXV));
        }
    }
    if (lane == 0) {
        atomicAdd(&acc[0], ll_acc);
        atomicAdd(&acc[1], comp_acc);
    }
}

__global__ void k_final(const float* __restrict__ acc, float* __restrict__ out) {
    if (threadIdx.x == 0) out[0] = acc[0] - (TMAXV * acc[2] + acc[1]);
}

extern "C" void kernel_launch(void* const* d_in, const int* in_sizes, int n_in,
                              void* d_out, int out_size, void* d_ws, size_t ws_size,
                              hipStream_t stream) {
    const float* t_ev = (const float*)d_in[0];
    const int* marks = (const int*)d_in[1];
    const float* log_mu = (const float*)d_in[2];
    const float* log_alpha = (const float*)d_in[3];
    float* out = (float*)d_out;

    float* w = (float*)d_ws;
    float* alpha = w;
    float* L = w + (size_t)D * D;
    float* mu = L + (size_t)NC * D;
    float* colsum = mu + D;
    float* acc = colsum + D;

    k_init<<<1, 256, 0, stream>>>(colsum, acc);
    k_prep<<<257, 256, 0, stream>>>(log_alpha, log_mu, alpha, mu, colsum, acc);
    k_buildL<<<NC, 256, 0, stream>>>(t_ev, marks, L);
    k_scan<<<4, 256, 0, stream>>>(t_ev, L);
    k_main<<<NC, 256, 0, stream>>>(t_ev, marks, alpha, mu, colsum, L, acc);
    k_final<<<1, 64, 0, stream>>>(acc, out);
}

// Round 2
// 153.518 us; speedup vs baseline: 1.1689x; 1.1689x over previous
//
#include <hip/hip_runtime.h>

// Hawkes log-likelihood, D=1024 dims, M=32768 events, BETA=1.
//
// lam_i = mu[d_i] + sum_{j<i} alpha[d_i,d_j] * exp(t_j - t_i).
// Chunk events into NC=512 chunks of C=64:
//   cross-chunk: exp(t_c0 - t_i) * dot(alpha[d_i,:], S_c)
//   in-chunk:    one lane-parallel predicated gather step (C == wave size)
// S_c via a TWO-LEVEL dimension-parallel scan (scalar decay factors =>
// group fixup is an FMA, fused into k_main's S load).
// Compensator: sum_i colsum(alpha)[d_i] * (1 - exp(t_i - T)), fused.
//
// ws floats: alpha[D*D] | L[NC*D] | mu[D] | colsum[D] | acc[4] |
//            A[16*D] | Sg[16*D] | cumdec[NC]

#define D 1024
#define M 32768
#define C 64
#define NC (M / C)  /* 512 */
#define NG 16       /* scan groups */
#define GC (NC / NG) /* 32 chunks per group */
#define TMAXV 1000.0f
#define EPSMU 1e-6f
#define EPSLOG 1e-8f

__device__ __forceinline__ float softplus(float x) {
    return (x > 0.0f) ? (x + log1pf(__expf(-x))) : log1pf(__expf(x));
}

__global__ void k_init(float* __restrict__ colsum, float* __restrict__ acc) {
    int t = threadIdx.x;
#pragma unroll
    for (int q = 0; q < 4; ++q) colsum[t + 256 * q] = 0.0f;
    if (t < 4) acc[t] = 0.0f;
}

// blocks 0..255: softplus(alpha) tile (4 rows x 1024 cols) + column-sum partials
// block 256: mu = softplus(log_mu) + eps, and mu_sum
__global__ void k_prep(const float* __restrict__ log_alpha, const float* __restrict__ log_mu,
                       float* __restrict__ alpha, float* __restrict__ mu,
                       float* __restrict__ colsum, float* __restrict__ acc) {
    int t = threadIdx.x;
    int b = blockIdx.x;
    if (b < 256) {
        int r0 = b * 4;
        float cs[4] = {0.f, 0.f, 0.f, 0.f};
        for (int r = 0; r < 4; ++r) {
            size_t base = (size_t)(r0 + r) * D;
#pragma unroll
            for (int q = 0; q < 4; ++q) {
                int col = t + 256 * q;
                float a = softplus(log_alpha[base + col]);
                alpha[base + col] = a;
                cs[q] += a;
            }
        }
#pragma unroll
        for (int q = 0; q < 4; ++q) atomicAdd(&colsum[t + 256 * q], cs[q]);
    } else {
        float ms = 0.0f;
#pragma unroll
        for (int q = 0; q < 4; ++q) {
            int k = t + 256 * q;
            float m = softplus(log_mu[k]) + EPSMU;
            mu[k] = m;
            ms += m;
        }
        atomicAdd(&acc[2], ms);
    }
}

// per-chunk local excitation histogram, referenced at next chunk's start time
__global__ void k_buildL(const float* __restrict__ t_ev, const int* __restrict__ marks,
                         float* __restrict__ L) {
    __shared__ float Lh[D];
    int t = threadIdx.x, c = blockIdx.x;
#pragma unroll
    for (int q = 0; q < 4; ++q) Lh[t + 256 * q] = 0.0f;
    __syncthreads();
    if (t < C) {
        int g = c * C + t;
        float tn = (c + 1 < NC) ? t_ev[(c + 1) * C] : t_ev[M - 1];
        atomicAdd(&Lh[marks[g]], __expf(t_ev[g] - tn));
    }
    __syncthreads();
#pragma unroll
    for (int q = 0; q < 4; ++q) {
        int k = t + 256 * q;
        L[(size_t)c * D + k] = Lh[k];
    }
}

// Level-1 scan: 64 blocks = 16 groups x 4 dim-slices of 256.
// In place: L[c] becomes local prefix Sl_c (group-start state = 0).
// A[g][d] = local state after the group's last chunk.
__global__ void k_scanA(const float* __restrict__ t_ev, float* __restrict__ L,
                        float* __restrict__ A) {
    __shared__ float dec[GC];
    int g = blockIdx.x >> 2, db = blockIdx.x & 3;
    int t = threadIdx.x;
    if (t < GC) {
        int c = g * GC + t;
        dec[t] = (c + 1 < NC) ? __expf(t_ev[c * C] - t_ev[(c + 1) * C]) : 1.0f;
    }
    __syncthreads();
    int k = db * 256 + t;
    float S = 0.0f;
    for (int u8 = 0; u8 < GC; u8 += 8) {
        float tmp[8];
#pragma unroll
        for (int u = 0; u < 8; ++u) tmp[u] = L[(size_t)(g * GC + u8 + u) * D + k];
#pragma unroll
        for (int u = 0; u < 8; ++u) {
            L[(size_t)(g * GC + u8 + u) * D + k] = S;
            S = S * dec[u8 + u] + tmp[u];
        }
    }
    A[(size_t)g * D + k] = S;
}

// Level-2 scan over the 16 group aggregates + per-chunk scalar cumdec.
// 1 block, 1024 threads (one per dimension).
__global__ void k_scanB(const float* __restrict__ t_ev, const float* __restrict__ A,
                        float* __restrict__ Sg, float* __restrict__ cumdec) {
    __shared__ float dec[NC];
    __shared__ float P[NG];
    int t = threadIdx.x;
    if (t < NC)
        dec[t] = (t + 1 < NC) ? __expf(t_ev[t * C] - t_ev[(t + 1) * C]) : 1.0f;
    __syncthreads();
    if (t < NC) {
        int g = t >> 5, r = t & 31;
        float p = 1.0f;
        for (int j = 0; j < r; ++j) p *= dec[g * GC + j];
        cumdec[t] = p;  // product of decs before chunk t within its group
        if (r == GC - 1) P[g] = p * dec[t];
    }
    __syncthreads();
    float a[NG];
#pragma unroll
    for (int g2 = 0; g2 < NG; ++g2) a[g2] = A[(size_t)g2 * D + t];
    float S = 0.0f;
#pragma unroll
    for (int g2 = 0; g2 < NG; ++g2) {
        Sg[(size_t)g2 * D + t] = S;  // group-start true state
        S = S * P[g2] + a[g2];
    }
}

// main: 4 blocks per chunk (16 events each), fused scan fixup + compensator
__launch_bounds__(256)
__global__ void k_main(const float* __restrict__ t_ev, const int* __restrict__ marks,
                       const float* __restrict__ alpha, const float* __restrict__ mu,
                       const float* __restrict__ colsum, const float* __restrict__ Sl,
                       const float* __restrict__ Sg, const float* __restrict__ cumdec,
                       float* __restrict__ acc) {
    __shared__ float S_lds[D];
    __shared__ float t_lds[C];
    __shared__ int d_lds[C];
    __shared__ float red[8];
    int t = threadIdx.x;
    int c = blockIdx.x >> 2, sub = blockIdx.x & 3;
    int g = c >> 5;
    float cd = cumdec[c];
#pragma unroll
    for (int q = 0; q < 4; ++q) {
        int k = t + 256 * q;
        S_lds[k] = Sl[(size_t)c * D + k] + Sg[(size_t)g * D + k] * cd;
    }
    if (t < C) {
        t_lds[t] = t_ev[c * C + t];
        d_lds[t] = marks[c * C + t];
    }
    __syncthreads();
    int wave = t >> 6, lane = t & 63;
    float t0 = t_lds[0];
    float ll_acc = 0.0f, comp_acc = 0.0f;
    for (int i = sub * 16 + wave; i < sub * 16 + 16; i += 4) {
        int row = d_lds[i];
        float ti = t_lds[i];
        float mu_r = mu[row];        // prefetch; used after the reduce
        float cs_r = colsum[row];
        const float4* arow = (const float4*)(alpha + (size_t)row * D);
        const float4* srow = (const float4*)S_lds;
        float acc_dot = 0.0f;
#pragma unroll
        for (int u = 0; u < 4; ++u) {
            float4 a4 = arow[lane + 64 * u];
            float4 s4 = srow[lane + 64 * u];
            acc_dot += a4.x * s4.x + a4.y * s4.y + a4.z * s4.z + a4.w * s4.w;
        }
        float part = acc_dot * __expf(t0 - ti);
        if (lane < i) {
            part += alpha[(size_t)row * D + d_lds[lane]] * __expf(t_lds[lane] - ti);
        }
#pragma unroll
        for (int off = 32; off > 0; off >>= 1) part += __shfl_xor(part, off);
        if (lane == 0) {
            float lam = mu_r + part;
            ll_acc += __logf(lam + EPSLOG);
            comp_acc += cs_r * (1.0f - __expf(ti - TMAXV));
        }
    }
    if (lane == 0) {
        red[wave] = ll_acc;
        red[4 + wave] = comp_acc;
    }
    __syncthreads();
    if (t == 0) {
        float l = red[0] + red[1] + red[2] + red[3];
        float cm = red[4] + red[5] + red[6] + red[7];
        atomicAdd(&acc[0], l);
        atomicAdd(&acc[1], cm);
    }
}

__global__ void k_final(const float* __restrict__ acc, float* __restrict__ out) {
    if (threadIdx.x == 0) out[0] = acc[0] - (TMAXV * acc[2] + acc[1]);
}

extern "C" void kernel_launch(void* const* d_in, const int* in_sizes, int n_in,
                              void* d_out, int out_size, void* d_ws, size_t ws_size,
                              hipStream_t stream) {
    const float* t_ev = (const float*)d_in[0];
    const int* marks = (const int*)d_in[1];
    const float* log_mu = (const float*)d_in[2];
    const float* log_alpha = (const float*)d_in[3];
    float* out = (float*)d_out;

    float* w = (float*)d_ws;
    float* alpha = w;                       // D*D
    float* L = alpha + (size_t)D * D;       // NC*D
    float* mu = L + (size_t)NC * D;         // D
    float* colsum = mu + D;                 // D
    float* acc = colsum + D;                // 4
    float* A = acc + 4;                     // NG*D
    float* Sg = A + (size_t)NG * D;         // NG*D
    float* cumdec = Sg + (size_t)NG * D;    // NC

    k_init<<<1, 256, 0, stream>>>(colsum, acc);
    k_prep<<<257, 256, 0, stream>>>(log_alpha, log_mu, alpha, mu, colsum, acc);
    k_buildL<<<NC, 256, 0, stream>>>(t_ev, marks, L);
    k_scanA<<<64, 256, 0, stream>>>(t_ev, L, A);
    k_scanB<<<1, 1024, 0, stream>>>(t_ev, A, Sg, cumdec);
    k_main<<<NC * 4, 256, 0, stream>>>(t_ev, marks, alpha, mu, colsum, L, Sg, cumdec, acc);
    k_final<<<1, 64, 0, stream>>>(acc, out);
}

// Round 4
// 112.619 us; speedup vs baseline: 1.5935x; 1.3632x over previous
//
#include <hip/hip_runtime.h>

// Hawkes log-likelihood, D=1024 dims, M=32768 events, BETA=1.
//
// lam_i = mu[d_i] + sum_{j<i} alpha[d_i,d_j] * exp(t_j - t_i).
// Chunk events into NC=512 chunks of C=64:
//   cross-chunk: exp(t_c0 - t_i) * dot(alpha[d_i,:], S_c)
//   in-chunk:    one lane-parallel predicated gather step (C == wave size)
// S_c via a TWO-LEVEL dimension-parallel scan (scalar decay factors =>
// group fixup is an FMA, fused into k_main's S load).
// Compensator: sum_i colsum(alpha)[d_i] * (1 - exp(t_i - T)), fused.
//
// R2 lesson: 4096 same-cacheline device atomics serialized at ~15ns each
// (~60us floor). This version has ZERO global atomics: per-block partials
// + dedicated reduction kernels.
//
// ws floats: alpha[D*D] | L[NC*D] | mu[D] | colsum[D] |
//            llp[NB] | compp[NB] | A[NG*D] | Sg[NG*D] | cumdec[NC]
// P (colsum partials, 256*D) ALIASES L: P is dead before k_buildL writes L
// (same-stream serialization). Keeps ws footprint at the R2-passing ~6.45 MB.

#define D 1024
#define M 32768
#define C 64
#define NC (M / C)   /* 512 */
#define NB (NC * 4)  /* k_main blocks: 2048 */
#define NG 16        /* scan groups */
#define GC (NC / NG) /* 32 chunks per group */
#define TMAXV 1000.0f
#define EPSMU 1e-6f
#define EPSLOG 1e-8f

__device__ __forceinline__ float softplus(float x) {
    return (x > 0.0f) ? (x + log1pf(__expf(-x))) : log1pf(__expf(x));
}

// blocks 0..255: softplus(alpha) tile (4 rows x 1024 cols) + per-block colsum
// partial (plain store, no atomics). block 256: mu = softplus(log_mu) + eps.
__global__ void k_prep(const float* __restrict__ log_alpha, const float* __restrict__ log_mu,
                       float* __restrict__ alpha, float* __restrict__ mu,
                       float* __restrict__ P) {
    int t = threadIdx.x;
    int b = blockIdx.x;
    if (b < 256) {
        int r0 = b * 4;
        float cs[4] = {0.f, 0.f, 0.f, 0.f};
        for (int r = 0; r < 4; ++r) {
            size_t base = (size_t)(r0 + r) * D;
#pragma unroll
            for (int q = 0; q < 4; ++q) {
                int col = t + 256 * q;
                float a = softplus(log_alpha[base + col]);
                alpha[base + col] = a;
                cs[q] += a;
            }
        }
#pragma unroll
        for (int q = 0; q < 4; ++q) P[(size_t)b * D + t + 256 * q] = cs[q];
    } else {
#pragma unroll
        for (int q = 0; q < 4; ++q) {
            int k = t + 256 * q;
            mu[k] = softplus(log_mu[k]) + EPSMU;
        }
    }
}

// reduce P[256][D] -> colsum[D]; 4 blocks x 256 threads, one column each
__global__ void k_colred(const float* __restrict__ P, float* __restrict__ colsum) {
    int col = blockIdx.x * 256 + threadIdx.x;
    float s = 0.0f;
#pragma unroll 8
    for (int r = 0; r < 256; ++r) s += P[(size_t)r * D + col];
    colsum[col] = s;
}

// per-chunk local excitation histogram, referenced at next chunk's start time
__global__ void k_buildL(const float* __restrict__ t_ev, const int* __restrict__ marks,
                         float* __restrict__ L) {
    __shared__ float Lh[D];
    int t = threadIdx.x, c = blockIdx.x;
#pragma unroll
    for (int q = 0; q < 4; ++q) Lh[t + 256 * q] = 0.0f;
    __syncthreads();
    if (t < C) {
        int g = c * C + t;
        float tn = (c + 1 < NC) ? t_ev[(c + 1) * C] : t_ev[M - 1];
        atomicAdd(&Lh[marks[g]], __expf(t_ev[g] - tn));  // LDS atomic: cheap
    }
    __syncthreads();
#pragma unroll
    for (int q = 0; q < 4; ++q) {
        int k = t + 256 * q;
        L[(size_t)c * D + k] = Lh[k];
    }
}

// Level-1 scan: 64 blocks = 16 groups x 4 dim-slices of 256.
// In place: L[c] becomes local prefix Sl_c (group-start state = 0).
// A[g][d] = local state after the group's last chunk.
__global__ void k_scanA(const float* __restrict__ t_ev, float* __restrict__ L,
                        float* __restrict__ A) {
    __shared__ float dec[GC];
    int g = blockIdx.x >> 2, db = blockIdx.x & 3;
    int t = threadIdx.x;
    if (t < GC) {
        int c = g * GC + t;
        dec[t] = (c + 1 < NC) ? __expf(t_ev[c * C] - t_ev[(c + 1) * C]) : 1.0f;
    }
    __syncthreads();
    int k = db * 256 + t;
    float S = 0.0f;
    for (int u8 = 0; u8 < GC; u8 += 8) {
        float tmp[8];
#pragma unroll
        for (int u = 0; u < 8; ++u) tmp[u] = L[(size_t)(g * GC + u8 + u) * D + k];
#pragma unroll
        for (int u = 0; u < 8; ++u) {
            L[(size_t)(g * GC + u8 + u) * D + k] = S;
            S = S * dec[u8 + u] + tmp[u];
        }
    }
    A[(size_t)g * D + k] = S;
}

// Level-2 scan over the 16 group aggregates + per-chunk scalar cumdec.
__global__ void k_scanB(const float* __restrict__ t_ev, const float* __restrict__ A,
                        float* __restrict__ Sg, float* __restrict__ cumdec) {
    __shared__ float dec[NC];
    __shared__ float P[NG];
    int t = threadIdx.x;
    if (t < NC)
        dec[t] = (t + 1 < NC) ? __expf(t_ev[t * C] - t_ev[(t + 1) * C]) : 1.0f;
    __syncthreads();
    if (t < NC) {
        int g = t >> 5, r = t & 31;
        float p = 1.0f;
        for (int j = 0; j < r; ++j) p *= dec[g * GC + j];
        cumdec[t] = p;
        if (r == GC - 1) P[g] = p * dec[t];
    }
    __syncthreads();
    float a[NG];
#pragma unroll
    for (int g2 = 0; g2 < NG; ++g2) a[g2] = A[(size_t)g2 * D + t];
    float S = 0.0f;
#pragma unroll
    for (int g2 = 0; g2 < NG; ++g2) {
        Sg[(size_t)g2 * D + t] = S;
        S = S * P[g2] + a[g2];
    }
}

// main: 4 blocks per chunk (16 events each), fused scan fixup + compensator.
// Per-block partials -> llp/compp (NO global atomics).
__launch_bounds__(256)
__global__ void k_main(const float* __restrict__ t_ev, const int* __restrict__ marks,
                       const float* __restrict__ alpha, const float* __restrict__ mu,
                       const float* __restrict__ colsum, const float* __restrict__ Sl,
                       const float* __restrict__ Sg, const float* __restrict__ cumdec,
                       float* __restrict__ llp, float* __restrict__ compp) {
    __shared__ float S_lds[D];
    __shared__ float t_lds[C];
    __shared__ int d_lds[C];
    __shared__ float red[8];
    int t = threadIdx.x;
    int c = blockIdx.x >> 2, sub = blockIdx.x & 3;
    int g = c >> 5;
    float cd = cumdec[c];
#pragma unroll
    for (int q = 0; q < 4; ++q) {
        int k = t + 256 * q;
        S_lds[k] = Sl[(size_t)c * D + k] + Sg[(size_t)g * D + k] * cd;
    }
    if (t < C) {
        t_lds[t] = t_ev[c * C + t];
        d_lds[t] = marks[c * C + t];
    }
    __syncthreads();
    int wave = t >> 6, lane = t & 63;
    float t0 = t_lds[0];
    float ll_acc = 0.0f, comp_acc = 0.0f;
    for (int i = sub * 16 + wave; i < sub * 16 + 16; i += 4) {
        int row = d_lds[i];
        float ti = t_lds[i];
        float mu_r = mu[row];
        float cs_r = colsum[row];
        const float4* arow = (const float4*)(alpha + (size_t)row * D);
        const float4* srow = (const float4*)S_lds;
        float acc_dot = 0.0f;
#pragma unroll
        for (int u = 0; u < 4; ++u) {
            float4 a4 = arow[lane + 64 * u];
            float4 s4 = srow[lane + 64 * u];
            acc_dot += a4.x * s4.x + a4.y * s4.y + a4.z * s4.z + a4.w * s4.w;
        }
        float part = acc_dot * __expf(t0 - ti);
        if (lane < i) {
            part += alpha[(size_t)row * D + d_lds[lane]] * __expf(t_lds[lane] - ti);
        }
#pragma unroll
        for (int off = 32; off > 0; off >>= 1) part += __shfl_xor(part, off);
        if (lane == 0) {
            float lam = mu_r + part;
            ll_acc += __logf(lam + EPSLOG);
            comp_acc += cs_r * (1.0f - __expf(ti - TMAXV));
        }
    }
    if (lane == 0) {
        red[wave] = ll_acc;
        red[4 + wave] = comp_acc;
    }
    __syncthreads();
    if (t == 0) {
        llp[blockIdx.x] = red[0] + red[1] + red[2] + red[3];
        compp[blockIdx.x] = red[4] + red[5] + red[6] + red[7];
    }
}

// final: reduce NB ll/comp partials + mu sum -> out. 1 block, 1024 threads.
__global__ void k_final(const float* __restrict__ llp, const float* __restrict__ compp,
                        const float* __restrict__ mu, float* __restrict__ out) {
    __shared__ float r_ll[1024], r_cm[1024], r_mu[1024];
    int t = threadIdx.x;
    float sll = llp[t] + llp[t + 1024];
    float scm = compp[t] + compp[t + 1024];
    r_ll[t] = sll;
    r_cm[t] = scm;
    r_mu[t] = mu[t];
    __syncthreads();
    for (int off = 512; off > 0; off >>= 1) {
        if (t < off) {
            r_ll[t] += r_ll[t + off];
            r_cm[t] += r_cm[t + off];
            r_mu[t] += r_mu[t + off];
        }
        __syncthreads();
    }
    if (t == 0) out[0] = r_ll[0] - (TMAXV * r_mu[0] + r_cm[0]);
}

extern "C" void kernel_launch(void* const* d_in, const int* in_sizes, int n_in,
                              void* d_out, int out_size, void* d_ws, size_t ws_size,
                              hipStream_t stream) {
    const float* t_ev = (const float*)d_in[0];
    const int* marks = (const int*)d_in[1];
    const float* log_mu = (const float*)d_in[2];
    const float* log_alpha = (const float*)d_in[3];
    float* out = (float*)d_out;

    float* w = (float*)d_ws;
    float* alpha = w;                       // D*D
    float* L = alpha + (size_t)D * D;       // NC*D
    float* mu = L + (size_t)NC * D;         // D
    float* colsum = mu + D;                 // D
    float* llp = colsum + D;                // NB
    float* compp = llp + NB;                // NB
    float* A = compp + NB;                  // NG*D
    float* Sg = A + (size_t)NG * D;         // NG*D
    float* cumdec = Sg + (size_t)NG * D;    // NC
    float* P = L;                           // ALIAS: dead before k_buildL writes L

    k_prep<<<257, 256, 0, stream>>>(log_alpha, log_mu, alpha, mu, P);
    k_colred<<<4, 256, 0, stream>>>(P, colsum);
    k_buildL<<<NC, 256, 0, stream>>>(t_ev, marks, L);
    k_scanA<<<64, 256, 0, stream>>>(t_ev, L, A);
    k_scanB<<<1, 1024, 0, stream>>>(t_ev, A, Sg, cumdec);
    k_main<<<NB, 256, 0, stream>>>(t_ev, marks, alpha, mu, colsum, L, Sg, cumdec, llp, compp);
    k_final<<<1, 1024, 0, stream>>>(llp, compp, mu, out);
}